// Round 5
// baseline (42.375 us; speedup 1.0000x reference)
//
#include <hip/hip_runtime.h>

// 9x9 clipped box-SUM on (8,3,1024,1024) f32 — fused, full-image-width blocks.
//
// Block = 256 threads; thread t owns the float4 at cols [4t, 4t+3] -> block
// spans all 1024 cols. Perfect 256B-aligned 1KB loads/stores per wave-row,
// zero horizontal halo fetch, zero wasted lanes (round 4 wasted 20% of its
// waves on strip overhang).
//
// Vertical: per-thread rolling 9-row window sum over a 16-row chunk, staged
// as r[25] with fully-static indices (rule #20: no breaks, no runtime
// indexing -> no scratch; tripwire = WRITE_SIZE staying ~97MB).
//
// Horizontal: thread t needs neighbor threads' V float4 (crosses wave
// boundaries) -> exchange V through a double-buffered LDS slab with ONE
// __syncthreads per row. Edge slots pre-zeroed = free image-edge clipping.

constexpr int H = 1024, W = 1024;
constexpr int RAD = 4;
constexpr int CHUNK = 16;
constexpr int NCHUNK = H / CHUNK;           // 64
constexpr int NIMG = 24;                    // 8 * 3
constexpr int NROWS = CHUNK + 2 * RAD + 1;  // 25
constexpr int TPB = 256;                    // = W/4, one float4 per thread

__global__ __launch_bounds__(TPB) void box9_kernel(const float* __restrict__ x,
                                                   float* __restrict__ out) {
    __shared__ float4 Vs[2][TPB + 2];

    const int t     = threadIdx.x;
    const int bid   = blockIdx.x;
    const int chunk = bid & (NCHUNK - 1);   // NCHUNK = 64
    const int img   = bid >> 6;

    const float* xp = x   + (size_t)img * (H * W) + 4 * t;
    float*       op = out + (size_t)img * (H * W) + 4 * t;
    const int h0 = chunk * CHUNK;

    // Image-edge halo slots: zero once (read only after the first barrier).
    if (t == 0) {
        Vs[0][0] = make_float4(0.f, 0.f, 0.f, 0.f);
        Vs[1][0] = make_float4(0.f, 0.f, 0.f, 0.f);
    }
    if (t == TPB - 1) {
        Vs[0][TPB + 1] = make_float4(0.f, 0.f, 0.f, 0.f);
        Vs[1][TPB + 1] = make_float4(0.f, 0.f, 0.f, 0.f);
    }

    // Stage the chunk + vertical halo: 25 independent 16B loads.
    float4 r[NROWS];
#pragma unroll
    for (int j = 0; j < NROWS; ++j) {
        const int row = h0 - RAD + j;
        r[j] = ((unsigned)row < (unsigned)H)
             ? *reinterpret_cast<const float4*>(xp + (size_t)row * W)
             : make_float4(0.f, 0.f, 0.f, 0.f);
    }

    // V = vertical 9-row window sum, init over rows h0-4 .. h0+4.
    float4 V = make_float4(0.f, 0.f, 0.f, 0.f);
#pragma unroll
    for (int j = 0; j < 9; ++j) {
        V.x += r[j].x; V.y += r[j].y; V.z += r[j].z; V.w += r[j].w;
    }

#pragma unroll
    for (int j = 0; j < CHUNK; ++j) {
        const int buf = j & 1;
        Vs[buf][t + 1] = V;
        __syncthreads();   // double buffer -> this is the only barrier per row
        const float4 VL = Vs[buf][t];
        const float4 VR = Vs[buf][t + 2];

        // Own total, left-neighbor suffix sums, right-neighbor prefix sums.
        const float T   = V.x + V.y + V.z + V.w;
        const float ls3 = VL.w;
        const float ls2 = ls3 + VL.z;
        const float ls1 = ls2 + VL.y;
        const float lT  = ls1 + VL.x;
        const float rp0 = VR.x;
        const float rp1 = rp0 + VR.y;
        const float rp2 = rp1 + VR.z;
        const float rT  = rp2 + VR.w;

        float4 o;
        o.x = lT  + T + rp0;   // col 4t   : window 4t-4 .. 4t+4
        o.y = ls1 + T + rp1;   // col 4t+1
        o.z = ls2 + T + rp2;   // col 4t+2
        o.w = ls3 + T + rT;    // col 4t+3 : window 4t-1 .. 4t+7
        *reinterpret_cast<float4*>(op + (size_t)(h0 + j) * W) = o;

        // Roll vertical window: add row h0+j+5, drop row h0+j-4 (static idx).
        V.x += r[j + 9].x - r[j].x;
        V.y += r[j + 9].y - r[j].y;
        V.z += r[j + 9].z - r[j].z;
        V.w += r[j + 9].w - r[j].w;
    }
}

extern "C" void kernel_launch(void* const* d_in, const int* in_sizes, int n_in,
                              void* d_out, int out_size, void* d_ws, size_t ws_size,
                              hipStream_t stream) {
    const float* x   = (const float*)d_in[0];
    float*       out = (float*)d_out;
    const int n_blocks = NIMG * NCHUNK;   // 24 * 64 = 1536, all fully productive
    box9_kernel<<<dim3(n_blocks), dim3(TPB), 0, stream>>>(x, out);
}